// Round 1
// baseline (6607.926 us; speedup 1.0000x reference)
//
#include <hip/hip_runtime.h>
#include <math.h>

#define QL 1024
#define BSZ 4
#define DM 512
#define NH 8
#define DHH 64
#define MEML 1024
#define KL 2048
#define DMLP 2048

// ---------------- GEMM: C[M,N] = A[M,K] @ W[N,K]^T (+bias, +relu) ----------
// A is virtually split: rows [0,M0) from A0, rows [M0,M) from A1.
// M,N multiples of 64; K multiple of 16.
template<bool BIAS, bool RELU>
__global__ __launch_bounds__(256)
void gemm_nt(const float* __restrict__ A0, const float* __restrict__ A1, int M0,
             const float* __restrict__ W, const float* __restrict__ bias,
             float* __restrict__ C, int M, int N, int K) {
  __shared__ float As[16][65];
  __shared__ float Bs[16][65];
  const int tid = threadIdx.x;
  const int tx = tid & 15, ty = tid >> 4;
  const int row0 = blockIdx.y * 64, col0 = blockIdx.x * 64;
  float acc[4][4] = {{0.f}};
  const int lr = tid >> 2;   // 0..63
  const int lc = tid & 3;    // 0..3
  const int grow = row0 + lr;
  const float* Arow = (grow < M0) ? (A0 + (size_t)grow * K)
                                  : (A1 + (size_t)(grow - M0) * K);
  const float* Wrow = W + (size_t)(col0 + lr) * K;
  for (int k0 = 0; k0 < K; k0 += 16) {
    float4 a4 = *(const float4*)(Arow + k0 + lc * 4);
    float4 b4 = *(const float4*)(Wrow + k0 + lc * 4);
    As[lc*4+0][lr] = a4.x; As[lc*4+1][lr] = a4.y;
    As[lc*4+2][lr] = a4.z; As[lc*4+3][lr] = a4.w;
    Bs[lc*4+0][lr] = b4.x; Bs[lc*4+1][lr] = b4.y;
    Bs[lc*4+2][lr] = b4.z; Bs[lc*4+3][lr] = b4.w;
    __syncthreads();
    #pragma unroll
    for (int kk = 0; kk < 16; ++kk) {
      float a[4], b[4];
      #pragma unroll
      for (int i2 = 0; i2 < 4; ++i2) a[i2] = As[kk][ty*4+i2];
      #pragma unroll
      for (int j2 = 0; j2 < 4; ++j2) b[j2] = Bs[kk][tx*4+j2];
      #pragma unroll
      for (int i2 = 0; i2 < 4; ++i2)
        #pragma unroll
        for (int j2 = 0; j2 < 4; ++j2)
          acc[i2][j2] += a[i2]*b[j2];
    }
    __syncthreads();
  }
  #pragma unroll
  for (int i2 = 0; i2 < 4; ++i2) {
    const int rr = row0 + ty*4 + i2;
    const int cc = col0 + tx*4;
    float4 o;
    o.x = acc[i2][0]; o.y = acc[i2][1]; o.z = acc[i2][2]; o.w = acc[i2][3];
    if (BIAS) { o.x += bias[cc]; o.y += bias[cc+1]; o.z += bias[cc+2]; o.w += bias[cc+3]; }
    if (RELU) {
      o.x = fmaxf(o.x, 0.f); o.y = fmaxf(o.y, 0.f);
      o.z = fmaxf(o.z, 0.f); o.w = fmaxf(o.w, 0.f);
    }
    *(float4*)(C + (size_t)rr * N + cc) = o;
  }
}

// ---------------- Attention: one block handles (i0,i0+1, b, h) -------------
// score[i,j] = 0.125*((q_i+u_h)·k_j + (q_i+v_h)·rk[j+1023-i])  for j<=i+MEM
// prob written to d_out layout [i,j,b,h]; attn (=prob@V) to ws [i*B+b, h*64+d]
__global__ __launch_bounds__(64)
void attn_kernel(const float* __restrict__ QKV, const float* __restrict__ RK,
                 const float* __restrict__ u, const float* __restrict__ v,
                 float* __restrict__ prob, float* __restrict__ attn) {
  const int i0 = blockIdx.x * 2;
  const int b  = blockIdx.y;
  const int h  = blockIdx.z;
  const int t  = threadIdx.x;

  __shared__ float qu[2][64], qv[2][64];
  __shared__ float kt[64][65];
  __shared__ float rt[65][65];
  __shared__ float sc[2][KL];
  __shared__ float red[64];

  #pragma unroll
  for (int r = 0; r < 2; ++r) {
    float qval = QKV[((size_t)(MEML + i0 + r) * BSZ + b) * 1536 + h * 64 + t];
    qu[r][t] = qval + u[h*64 + t];
    qv[r][t] = qval + v[h*64 + t];
  }
  const int jmax0 = i0 + MEML;       // inclusive
  const int jmax1 = jmax0 + 1;
  for (int j = t; j < KL; j += 64) {
    if (j > jmax0) sc[0][j] = -1e30f;
    if (j > jmax1) sc[1][j] = -1e30f;
  }
  __syncthreads();

  const int ntiles = jmax1 / 64 + 1;
  const int rtbase = 1022 - i0;      // jr(row rr of tile j0) = j0 + rtbase + rr
  for (int tile = 0; tile < ntiles; ++tile) {
    const int j0 = tile * 64;
    for (int p = t; p < 64*16; p += 64) {
      const int rr = p >> 4, cc = (p & 15) * 4;
      const float4 k4 = *(const float4*)(QKV + ((size_t)(j0+rr)*BSZ + b)*1536 + 512 + h*64 + cc);
      kt[rr][cc] = k4.x; kt[rr][cc+1] = k4.y; kt[rr][cc+2] = k4.z; kt[rr][cc+3] = k4.w;
    }
    for (int p = t; p < 65*16; p += 64) {
      const int rr = p >> 4, cc = (p & 15) * 4;
      const int jr = j0 + rtbase + rr;
      float4 r4 = make_float4(0.f, 0.f, 0.f, 0.f);
      if (jr < KL) r4 = *(const float4*)(RK + (size_t)jr*DM + h*64 + cc);
      rt[rr][cc] = r4.x; rt[rr][cc+1] = r4.y; rt[rr][cc+2] = r4.z; rt[rr][cc+3] = r4.w;
    }
    __syncthreads();
    const int j = j0 + t;
    float ac0 = 0.f, ac1 = 0.f, bd0 = 0.f, bd1 = 0.f;
    #pragma unroll
    for (int d = 0; d < 64; ++d) {
      const float kv = kt[t][d];
      const float r1 = rt[t][d];      // jr = j+1023-(i0+1)
      const float r0 = rt[t+1][d];    // jr = j+1023-i0
      ac0 += qu[0][d]*kv; ac1 += qu[1][d]*kv;
      bd0 += qv[0][d]*r0; bd1 += qv[1][d]*r1;
    }
    if (j <= jmax0) sc[0][j] = 0.125f*(ac0+bd0);
    if (j <= jmax1) sc[1][j] = 0.125f*(ac1+bd1);
    __syncthreads();
  }

  // softmax + prob write (exact: masked entries come out 0 like the ref)
  #pragma unroll
  for (int r = 0; r < 2; ++r) {
    float lm = -1e30f;
    for (int j = t; j < KL; j += 64) lm = fmaxf(lm, sc[r][j]);
    red[t] = lm; __syncthreads();
    for (int s = 32; s > 0; s >>= 1) { if (t < s) red[t] = fmaxf(red[t], red[t+s]); __syncthreads(); }
    const float m = red[0]; __syncthreads();
    float ls = 0.f;
    for (int j = t; j < KL; j += 64) { float e = __expf(sc[r][j] - m); sc[r][j] = e; ls += e; }
    red[t] = ls; __syncthreads();
    for (int s = 32; s > 0; s >>= 1) { if (t < s) red[t] += red[t+s]; __syncthreads(); }
    const float inv = 1.0f / red[0]; __syncthreads();
    const size_t iq = i0 + r;
    for (int j = t; j < KL; j += 64) {
      const float p = sc[r][j] * inv; sc[r][j] = p;
      prob[((iq*KL + j)*BSZ + b)*NH + h] = p;
    }
  }
  __syncthreads();

  // PV: attn[i, b, h*64+d] = sum_j prob[j] * V[j][d]
  float acc0 = 0.f, acc1 = 0.f;
  for (int tile = 0; tile < ntiles; ++tile) {
    const int j0 = tile * 64;
    for (int p = t; p < 64*16; p += 64) {
      const int rr = p >> 4, cc = (p & 15) * 4;
      const float4 v4 = *(const float4*)(QKV + ((size_t)(j0+rr)*BSZ + b)*1536 + 1024 + h*64 + cc);
      kt[rr][cc] = v4.x; kt[rr][cc+1] = v4.y; kt[rr][cc+2] = v4.z; kt[rr][cc+3] = v4.w;
    }
    __syncthreads();
    #pragma unroll
    for (int jj = 0; jj < 64; ++jj) {
      const float vv = kt[jj][t];
      acc0 += sc[0][j0+jj]*vv;
      acc1 += sc[1][j0+jj]*vv;
    }
    __syncthreads();
  }
  attn[((size_t)i0*BSZ + b)*DM + h*64 + t]     = acc0;
  attn[((size_t)(i0+1)*BSZ + b)*DM + h*64 + t] = acc1;
}

// ---------------- Residual + LayerNorm: y = LN(xa+xb)*g + b ----------------
__global__ __launch_bounds__(256)
void ln_res_kernel(const float* __restrict__ xa, const float* __restrict__ xb,
                   const float* __restrict__ g, const float* __restrict__ bb,
                   float* __restrict__ y) {
  const int rrow = blockIdx.x;
  const int t = threadIdx.x;
  const size_t base = (size_t)rrow * DM;
  __shared__ float red[256];
  const float a0 = xa[base + t]       + xb[base + t];
  const float a1 = xa[base + t + 256] + xb[base + t + 256];
  red[t] = a0 + a1; __syncthreads();
  for (int s = 128; s > 0; s >>= 1) { if (t < s) red[t] += red[t+s]; __syncthreads(); }
  const float mu = red[0] * (1.0f/512.0f);
  __syncthreads();
  red[t] = a0*a0 + a1*a1; __syncthreads();
  for (int s = 128; s > 0; s >>= 1) { if (t < s) red[t] += red[t+s]; __syncthreads(); }
  const float var = red[0] * (1.0f/512.0f) - mu*mu;
  const float w = rsqrtf(var + 1e-5f);
  y[base + t]       = (a0 - mu) * w * g[t]       + bb[t];
  y[base + t + 256] = (a1 - mu) * w * g[t + 256] + bb[t + 256];
}

extern "C" void kernel_launch(void* const* d_in, const int* in_sizes, int n_in,
                              void* d_out, int out_size, void* d_ws, size_t ws_size,
                              hipStream_t stream) {
  const float* inputs = (const float*)d_in[0];
  const float* r      = (const float*)d_in[1];
  const float* u      = (const float*)d_in[2];
  const float* v      = (const float*)d_in[3];
  const float* mem    = (const float*)d_in[4];
  // d_in[5] attn_mask: derived on device (j > i+MEM), unused
  const float* Wqkv   = (const float*)d_in[6];
  const float* Wr     = (const float*)d_in[7];
  const float* Wo     = (const float*)d_in[8];
  const float* ln1g   = (const float*)d_in[9];
  const float* ln1b   = (const float*)d_in[10];
  const float* w1     = (const float*)d_in[11];
  const float* b1     = (const float*)d_in[12];
  const float* w2     = (const float*)d_in[13];
  const float* b2     = (const float*)d_in[14];
  const float* ln2g   = (const float*)d_in[15];
  const float* ln2b   = (const float*)d_in[16];

  float* out  = (float*)d_out;              // [1024,4,512]
  float* prob = out + (size_t)QL*BSZ*DM;    // [1024,2048,4,8]

  // Workspace layout (floats). Peak 19,922,944 floats = 79.7 MB.
  float* ws   = (float*)d_ws;
  float* QKV  = ws;                          // 8192*1536 = 12,582,912
  float* RK   = QKV + 12582912;              // 2048*512  =  1,048,576
  float* ATTN = RK + 1048576;                // 4096*512  =  2,097,152
  float* AO   = ATTN + 2097152;              // 4096*512
  float* Y    = AO + 2097152;                // 4096*512
  float* HM   = QKV;                         // reuse QKV (dead after attn): 4096*2048 = 8,388,608
  float* Z    = QKV + 8388608;               // 4096*512 (fits inside QKV region)

  const dim3 blk256(256);

  // qkv = [mem;inputs] @ Wqkv^T   [8192,1536]
  gemm_nt<false,false><<<dim3(1536/64, 8192/64), blk256, 0, stream>>>(
      mem, inputs, 4096, Wqkv, nullptr, QKV, 8192, 1536, 512);
  // rk = r @ Wr^T                 [2048,512]
  gemm_nt<false,false><<<dim3(512/64, 2048/64), blk256, 0, stream>>>(
      r, r, 2048, Wr, nullptr, RK, 2048, 512, 512);
  // attention + softmax + prob write + PV
  attn_kernel<<<dim3(QL/2, BSZ, NH), dim3(64), 0, stream>>>(QKV, RK, u, v, prob, ATTN);
  // attn_out = attn @ Wo^T        [4096,512]
  gemm_nt<false,false><<<dim3(512/64, 4096/64), blk256, 0, stream>>>(
      ATTN, ATTN, 4096, Wo, nullptr, AO, 4096, 512, 512);
  // y = LN(inputs + attn_out)
  ln_res_kernel<<<dim3(4096), blk256, 0, stream>>>(inputs, AO, ln1g, ln1b, Y);
  // h = relu(y @ w1^T + b1)       [4096,2048]
  gemm_nt<true,true><<<dim3(2048/64, 4096/64), blk256, 0, stream>>>(
      Y, Y, 4096, w1, b1, HM, 4096, 2048, 512);
  // z = h @ w2^T + b2             [4096,512]
  gemm_nt<true,false><<<dim3(512/64, 4096/64), blk256, 0, stream>>>(
      HM, HM, 4096, w2, b2, Z, 4096, 512, 2048);
  // out = LN(y + z)
  ln_res_kernel<<<dim3(4096), blk256, 0, stream>>>(Y, Z, ln2g, ln2b, out);
}

// Round 2
// 1923.507 us; speedup vs baseline: 3.4354x; 3.4354x over previous
//
#include <hip/hip_runtime.h>
#include <math.h>

#define QL 1024
#define BSZ 4
#define DM 512
#define NH 8
#define DHH 64
#define MEML 1024
#define KL 2048
#define DMLP 2048

// ---------------- GEMM: C[M,N] = A[M,K] @ W[N,K]^T (+bias, +relu) ----------
template<bool BIAS, bool RELU>
__global__ __launch_bounds__(256)
void gemm_nt(const float* __restrict__ A0, const float* __restrict__ A1, int M0,
             const float* __restrict__ W, const float* __restrict__ bias,
             float* __restrict__ C, int M, int N, int K) {
  __shared__ float As[16][65];
  __shared__ float Bs[16][65];
  const int tid = threadIdx.x;
  const int tx = tid & 15, ty = tid >> 4;
  const int row0 = blockIdx.y * 64, col0 = blockIdx.x * 64;
  float acc[4][4] = {{0.f}};
  const int lr = tid >> 2;
  const int lc = tid & 3;
  const int grow = row0 + lr;
  const float* Arow = (grow < M0) ? (A0 + (size_t)grow * K)
                                  : (A1 + (size_t)(grow - M0) * K);
  const float* Wrow = W + (size_t)(col0 + lr) * K;
  for (int k0 = 0; k0 < K; k0 += 16) {
    float4 a4 = *(const float4*)(Arow + k0 + lc * 4);
    float4 b4 = *(const float4*)(Wrow + k0 + lc * 4);
    As[lc*4+0][lr] = a4.x; As[lc*4+1][lr] = a4.y;
    As[lc*4+2][lr] = a4.z; As[lc*4+3][lr] = a4.w;
    Bs[lc*4+0][lr] = b4.x; Bs[lc*4+1][lr] = b4.y;
    Bs[lc*4+2][lr] = b4.z; Bs[lc*4+3][lr] = b4.w;
    __syncthreads();
    #pragma unroll
    for (int kk = 0; kk < 16; ++kk) {
      float a[4], b[4];
      #pragma unroll
      for (int i2 = 0; i2 < 4; ++i2) a[i2] = As[kk][ty*4+i2];
      #pragma unroll
      for (int j2 = 0; j2 < 4; ++j2) b[j2] = Bs[kk][tx*4+j2];
      #pragma unroll
      for (int i2 = 0; i2 < 4; ++i2)
        #pragma unroll
        for (int j2 = 0; j2 < 4; ++j2)
          acc[i2][j2] += a[i2]*b[j2];
    }
    __syncthreads();
  }
  #pragma unroll
  for (int i2 = 0; i2 < 4; ++i2) {
    const int rr = row0 + ty*4 + i2;
    const int cc = col0 + tx*4;
    float4 o;
    o.x = acc[i2][0]; o.y = acc[i2][1]; o.z = acc[i2][2]; o.w = acc[i2][3];
    if (BIAS) { o.x += bias[cc]; o.y += bias[cc+1]; o.z += bias[cc+2]; o.w += bias[cc+3]; }
    if (RELU) {
      o.x = fmaxf(o.x, 0.f); o.y = fmaxf(o.y, 0.f);
      o.z = fmaxf(o.z, 0.f); o.w = fmaxf(o.w, 0.f);
    }
    *(float4*)(C + (size_t)rr * N + cc) = o;
  }
}

// ---------------- uk[b,h,j] = u_h . k_jbh ; vr[h,jr] = v_h . rk_jr,h --------
__global__ __launch_bounds__(256)
void ukvr_kernel(const float* __restrict__ QKV, const float* __restrict__ RK,
                 const float* __restrict__ u, const float* __restrict__ v,
                 float* __restrict__ UK, float* __restrict__ VR) {
  const int id = blockIdx.x * 256 + threadIdx.x;
  if (id < 65536) {
    const int bh = id >> 11, j = id & 2047;
    const int b = bh >> 3, h = bh & 7;
    const float* kp = QKV + ((size_t)j * 4 + b) * 1536 + 512 + h * 64;
    const float* up = u + h * 64;
    float s = 0.f;
    #pragma unroll
    for (int d = 0; d < 64; ++d) s += up[d] * kp[d];
    UK[id] = s;
  } else if (id < 65536 + 16384) {
    const int e = id - 65536;
    const int h = e >> 11, jr = e & 2047;
    const float* rp = RK + (size_t)jr * 512 + h * 64;
    const float* vp = v + h * 64;
    float s = 0.f;
    #pragma unroll
    for (int d = 0; d < 64; ++d) s += vp[d] * rp[d];
    VR[e] = s;
  }
}

__device__ __forceinline__ unsigned int bf16rne(float f) {
  unsigned int b = __float_as_uint(f);
  return (b + 0x7fffu + ((b >> 16) & 1u)) >> 16;
}

// ---------------- Attention: block = (64 q-rows, b, h), GEMM-tiled ---------
__global__ __launch_bounds__(256)
void attn2_kernel(const float* __restrict__ QKV, const float* __restrict__ RK,
                  const float* __restrict__ UK, const float* __restrict__ VR,
                  unsigned short* __restrict__ P, float* __restrict__ INV,
                  float* __restrict__ ATTN) {
  const int i0 = (15 - blockIdx.x) * 64;   // longest blocks first
  const int b  = blockIdx.y;
  const int h  = blockIdx.z;
  const int t  = threadIdx.x;
  const int tx = t & 15, ty = t >> 4;

  __shared__ float Qs[64][65];     // [d][i]
  __shared__ float Ks[64][65];     // K: [d][j]; V: [j][d]
  __shared__ float Rs[64][65];     // [d][jr_local]
  __shared__ float Ring[64][130];  // [i][ring col]
  __shared__ float Es[64][65];     // [j][i]
  __shared__ float uks[64];
  __shared__ float vrs[128];
  __shared__ float red[16][68];
  __shared__ float invs[64];

  // ---- load Q tile (transposed to [d][i]) ----
  for (int p = t; p < 1024; p += 256) {
    const int rr = p >> 4, cc = (p & 15) * 4;
    const float4 q4 = *(const float4*)(QKV + ((size_t)(MEML + i0 + rr) * 4 + b) * 1536 + h * 64 + cc);
    Qs[cc][rr] = q4.x; Qs[cc+1][rr] = q4.y; Qs[cc+2][rr] = q4.z; Qs[cc+3][rr] = q4.w;
  }

  // ---- prologue: BD tile for jr0 = 960 - i0 into ring slot 1 ----
  {
    const int jr0p = 960 - i0;
    for (int p = t; p < 1024; p += 256) {
      const int rr = p >> 4, cc = (p & 15) * 4;
      const float4 r4 = *(const float4*)(RK + (size_t)(jr0p + rr) * 512 + h * 64 + cc);
      Rs[cc][rr] = r4.x; Rs[cc+1][rr] = r4.y; Rs[cc+2][rr] = r4.z; Rs[cc+3][rr] = r4.w;
    }
    __syncthreads();
    float bd[4][4] = {{0.f}};
    #pragma unroll 8
    for (int kk = 0; kk < 64; ++kk) {
      const float4 a = *(const float4*)&Qs[kk][ty*4];
      const float4 rb = *(const float4*)&Rs[kk][tx*4];
      const float av[4] = {a.x, a.y, a.z, a.w};
      const float rv[4] = {rb.x, rb.y, rb.z, rb.w};
      #pragma unroll
      for (int ii = 0; ii < 4; ++ii)
        #pragma unroll
        for (int jj = 0; jj < 4; ++jj)
          bd[ii][jj] += av[ii] * rv[jj];
    }
    #pragma unroll
    for (int ii = 0; ii < 4; ++ii)
      #pragma unroll
      for (int jj = 0; jj < 4; ++jj)
        Ring[ty*4+ii][64 + tx*4+jj] = bd[ii][jj];
  }

  float pv[4][4] = {{0.f}};
  float rs[4] = {0.f, 0.f, 0.f, 0.f};

  const int ntiles = i0 / 64 + 17;
  for (int n = 0; n < ntiles; ++n) {
    const int j0 = n * 64;
    const int jr0 = j0 - i0 + 1024;
    __syncthreads();   // prior iter done with Ks/Es/Ring slots
    // ---- stage K (transposed) and R (transposed) ----
    for (int p = t; p < 1024; p += 256) {
      const int rr = p >> 4, cc = (p & 15) * 4;
      const float4 k4 = *(const float4*)(QKV + ((size_t)(j0 + rr) * 4 + b) * 1536 + 512 + h * 64 + cc);
      Ks[cc][rr] = k4.x; Ks[cc+1][rr] = k4.y; Ks[cc+2][rr] = k4.z; Ks[cc+3][rr] = k4.w;
      const int jr = jr0 + rr;
      float4 r4 = make_float4(0.f, 0.f, 0.f, 0.f);
      if (jr < 2048) r4 = *(const float4*)(RK + (size_t)jr * 512 + h * 64 + cc);
      Rs[cc][rr] = r4.x; Rs[cc+1][rr] = r4.y; Rs[cc+2][rr] = r4.z; Rs[cc+3][rr] = r4.w;
    }
    if (t < 64) uks[t] = UK[((size_t)(b * 8 + h) * 2048) + j0 + t];
    if (t < 128) {
      const int jr = j0 - i0 + 960 + t;
      vrs[t] = (jr < 2048) ? VR[h * 2048 + jr] : 0.f;
    }
    __syncthreads();
    // ---- AC and BD GEMMs ----
    float acc[4][4] = {{0.f}};
    float bd[4][4] = {{0.f}};
    #pragma unroll 8
    for (int kk = 0; kk < 64; ++kk) {
      const float4 a = *(const float4*)&Qs[kk][ty*4];
      const float4 kb = *(const float4*)&Ks[kk][tx*4];
      const float4 rb = *(const float4*)&Rs[kk][tx*4];
      const float av[4] = {a.x, a.y, a.z, a.w};
      const float kv[4] = {kb.x, kb.y, kb.z, kb.w};
      const float rv[4] = {rb.x, rb.y, rb.z, rb.w};
      #pragma unroll
      for (int ii = 0; ii < 4; ++ii)
        #pragma unroll
        for (int jj = 0; jj < 4; ++jj) {
          acc[ii][jj] += av[ii] * kv[jj];
          bd[ii][jj]  += av[ii] * rv[jj];
        }
    }
    const int base_cur  = (n & 1) * 64;
    const int base_prev = ((n + 1) & 1) * 64;
    #pragma unroll
    for (int ii = 0; ii < 4; ++ii)
      #pragma unroll
      for (int jj = 0; jj < 4; ++jj)
        Ring[ty*4+ii][base_cur + tx*4+jj] = bd[ii][jj];
    __syncthreads();
    // ---- assemble scores, exp, write Es + P ----
    #pragma unroll
    for (int ii = 0; ii < 4; ++ii) {
      const int ig = i0 + ty*4 + ii;
      float ev[4];
      #pragma unroll
      for (int jj = 0; jj < 4; ++jj) {
        const int jg = j0 + tx*4 + jj;
        const int jr_rel = (tx*4+jj) - (ty*4+ii) + 63;
        const float ringv = (jr_rel < 64) ? Ring[ty*4+ii][base_prev + jr_rel]
                                          : Ring[ty*4+ii][base_cur + jr_rel - 64];
        const float s = 0.125f * (acc[ii][jj] + ringv + uks[tx*4+jj] + vrs[jr_rel]);
        const float e = (jg > ig + MEML) ? 0.f : __expf(s);
        rs[ii] += e;
        Es[tx*4+jj][ty*4+ii] = e;
        ev[jj] = e;
      }
      uint2 pk;
      pk.x = bf16rne(ev[0]) | (bf16rne(ev[1]) << 16);
      pk.y = bf16rne(ev[2]) | (bf16rne(ev[3]) << 16);
      *(uint2*)(P + ((size_t)(b * 8 + h) * 1024 + ig) * 2048 + j0 + tx*4) = pk;
    }
    __syncthreads();
    // ---- stage V (natural [j][d]) into Ks ----
    for (int p = t; p < 1024; p += 256) {
      const int rr = p >> 4, cc = (p & 15) * 4;
      const float4 v4 = *(const float4*)(QKV + ((size_t)(j0 + rr) * 4 + b) * 1536 + 1024 + h * 64 + cc);
      Ks[rr][cc] = v4.x; Ks[rr][cc+1] = v4.y; Ks[rr][cc+2] = v4.z; Ks[rr][cc+3] = v4.w;
    }
    __syncthreads();
    // ---- PV GEMM ----
    #pragma unroll 8
    for (int jj = 0; jj < 64; ++jj) {
      const float4 a = *(const float4*)&Es[jj][ty*4];
      const float4 vb = *(const float4*)&Ks[jj][tx*4];
      const float av[4] = {a.x, a.y, a.z, a.w};
      const float vv[4] = {vb.x, vb.y, vb.z, vb.w};
      #pragma unroll
      for (int ii = 0; ii < 4; ++ii)
        #pragma unroll
        for (int dd = 0; dd < 4; ++dd)
          pv[ii][dd] += av[ii] * vv[dd];
    }
  }

  // ---- row sums -> inv; scale PV; store ----
  #pragma unroll
  for (int ii = 0; ii < 4; ++ii) red[tx][ty*4+ii] = rs[ii];
  __syncthreads();
  if (t < 64) {
    float s = 0.f;
    #pragma unroll
    for (int x = 0; x < 16; ++x) s += red[x][t];
    const float iv = 1.0f / s;
    invs[t] = iv;
    INV[(size_t)(b * 8 + h) * 1024 + i0 + t] = iv;
  }
  __syncthreads();
  #pragma unroll
  for (int ii = 0; ii < 4; ++ii) {
    const float iv = invs[ty*4+ii];
    float4 o;
    o.x = pv[ii][0]*iv; o.y = pv[ii][1]*iv; o.z = pv[ii][2]*iv; o.w = pv[ii][3]*iv;
    *(float4*)(ATTN + ((size_t)(i0 + ty*4 + ii) * 4 + b) * 512 + h * 64 + tx*4) = o;
  }
}

// ---------------- normalize + transpose P[b,h,i,j](bf16) -> prob[i,j,b,h] --
__global__ __launch_bounds__(256)
void ptrans_kernel(const unsigned short* __restrict__ P, const float* __restrict__ INV,
                   float* __restrict__ prob) {
  const int i  = blockIdx.x;
  const int j0 = blockIdx.y * 64;
  const int t  = threadIdx.x;
  __shared__ float tile[32][65];
  __shared__ float invs[32];
  const bool valid = j0 <= (i & ~63) + MEML;
  if (t < 32) invs[t] = INV[(size_t)t * 1024 + i];
  if (valid) {
    const int bh = t >> 3, part = t & 7;
    const uint4 raw = *(const uint4*)(P + ((size_t)bh * 1024 + i) * 2048 + j0 + part * 8);
    const unsigned int w[4] = {raw.x, raw.y, raw.z, raw.w};
    #pragma unroll
    for (int k = 0; k < 4; ++k) {
      tile[bh][part*8 + 2*k]     = __uint_as_float(w[k] << 16);
      tile[bh][part*8 + 2*k + 1] = __uint_as_float(w[k] & 0xffff0000u);
    }
  }
  __syncthreads();
  #pragma unroll
  for (int it = 0; it < 8; ++it) {
    const int idx = it * 256 + t;
    const int jl = idx >> 5, bh = idx & 31;
    const float val = valid ? tile[bh][jl] * invs[bh] : 0.f;
    prob[((size_t)i * 2048 + j0 + jl) * 32 + bh] = val;
  }
}

// ---------------- Residual + LayerNorm ----------------
__global__ __launch_bounds__(256)
void ln_res_kernel(const float* __restrict__ xa, const float* __restrict__ xb,
                   const float* __restrict__ g, const float* __restrict__ bb,
                   float* __restrict__ y) {
  const int rrow = blockIdx.x;
  const int t = threadIdx.x;
  const size_t base = (size_t)rrow * DM;
  __shared__ float red[256];
  const float a0 = xa[base + t]       + xb[base + t];
  const float a1 = xa[base + t + 256] + xb[base + t + 256];
  red[t] = a0 + a1; __syncthreads();
  for (int s = 128; s > 0; s >>= 1) { if (t < s) red[t] += red[t+s]; __syncthreads(); }
  const float mu = red[0] * (1.0f/512.0f);
  __syncthreads();
  red[t] = a0*a0 + a1*a1; __syncthreads();
  for (int s = 128; s > 0; s >>= 1) { if (t < s) red[t] += red[t+s]; __syncthreads(); }
  const float var = red[0] * (1.0f/512.0f) - mu*mu;
  const float w = rsqrtf(var + 1e-5f);
  y[base + t]       = (a0 - mu) * w * g[t]       + bb[t];
  y[base + t + 256] = (a1 - mu) * w * g[t + 256] + bb[t + 256];
}

extern "C" void kernel_launch(void* const* d_in, const int* in_sizes, int n_in,
                              void* d_out, int out_size, void* d_ws, size_t ws_size,
                              hipStream_t stream) {
  const float* inputs = (const float*)d_in[0];
  const float* r      = (const float*)d_in[1];
  const float* u      = (const float*)d_in[2];
  const float* v      = (const float*)d_in[3];
  const float* mem    = (const float*)d_in[4];
  const float* Wqkv   = (const float*)d_in[6];
  const float* Wr     = (const float*)d_in[7];
  const float* Wo     = (const float*)d_in[8];
  const float* ln1g   = (const float*)d_in[9];
  const float* ln1b   = (const float*)d_in[10];
  const float* w1     = (const float*)d_in[11];
  const float* b1     = (const float*)d_in[12];
  const float* w2     = (const float*)d_in[13];
  const float* b2     = (const float*)d_in[14];
  const float* ln2g   = (const float*)d_in[15];
  const float* ln2b   = (const float*)d_in[16];

  float* out  = (float*)d_out;              // [1024,4,512]
  float* prob = out + (size_t)QL*BSZ*DM;    // [1024,2048,4,8]

  // Workspace (floats). P(bf16) = 33,554,432 float-slots; total ~214 MB.
  float* ws   = (float*)d_ws;
  unsigned short* P = (unsigned short*)ws;   // [4*8][1024][2048] bf16
  float* QKV  = ws + 33554432;               // 8192*1536
  float* RK   = QKV + 12582912;              // 2048*512
  float* ATTN = RK + 1048576;                // 4096*512
  float* AO   = ATTN + 2097152;              // 4096*512
  float* Y    = AO + 2097152;                // 4096*512
  float* UK   = Y + 2097152;                 // 65536
  float* VR   = UK + 65536;                  // 16384
  float* INV  = VR + 16384;                  // 32768
  float* HM   = ws;                          // alias P (dead after ptrans): 4096*2048
  float* Z    = ws + 8388608;                // inside P region

  const dim3 blk256(256);

  gemm_nt<false,false><<<dim3(1536/64, 8192/64), blk256, 0, stream>>>(
      mem, inputs, 4096, Wqkv, nullptr, QKV, 8192, 1536, 512);
  gemm_nt<false,false><<<dim3(512/64, 2048/64), blk256, 0, stream>>>(
      r, r, 2048, Wr, nullptr, RK, 2048, 512, 512);
  ukvr_kernel<<<dim3(320), blk256, 0, stream>>>(QKV, RK, u, v, UK, VR);
  attn2_kernel<<<dim3(16, BSZ, NH), blk256, 0, stream>>>(QKV, RK, UK, VR, P, INV, ATTN);
  ptrans_kernel<<<dim3(1024, 32), blk256, 0, stream>>>(P, INV, prob);
  gemm_nt<false,false><<<dim3(512/64, 4096/64), blk256, 0, stream>>>(
      ATTN, ATTN, 4096, Wo, nullptr, AO, 4096, 512, 512);
  ln_res_kernel<<<dim3(4096), blk256, 0, stream>>>(inputs, AO, ln1g, ln1b, Y);
  gemm_nt<true,true><<<dim3(2048/64, 4096/64), blk256, 0, stream>>>(
      Y, Y, 4096, w1, b1, HM, 4096, 2048, 512);
  gemm_nt<true,false><<<dim3(512/64, 4096/64), blk256, 0, stream>>>(
      HM, HM, 4096, w2, b2, Z, 4096, 512, 2048);
  ln_res_kernel<<<dim3(4096), blk256, 0, stream>>>(Y, Z, ln2g, ln2b, out);
}